// Round 9
// baseline (11634.107 us; speedup 1.0000x reference)
//
#include <hip/hip_runtime.h>
#include <cstdint>

// Reference semantics (validated R8, absmax=0.0 — DO NOT change arithmetic):
//  - selection on RAW f32 coords, distance = fma(dz,dz, fma(dx,dx, dy*dy))
//    with dx/dy/dz plain f32 subs (XLA/LLVM FMA-contraction order);
//  - min/argmax exact, first-index tie-break;
//  - output coords bf16-RNE-rounded (ref Output-0 is bf16-grid), batch = float b.
#pragma clang fp contract(off)

#define B_ 16
#define N_ 16384
#define K_ 4096
#define THREADS_ 1024
#define PTS_ (N_ / THREADS_)   // 16 points per thread -> arrays fit in VGPRs
#define NW_ (THREADS_ / 64)    // 16 waves per block

// f32 -> bf16 RNE, returned as the bf16-representable f32 (finite inputs)
__device__ __forceinline__ float bfr(float f) {
  union { float f; uint32_t i; } c; c.f = f;
  c.i = (c.i + 0x7FFFu + ((c.i >> 16) & 1u)) & 0xFFFF0000u;
  return c.f;
}

// FMA-V1 squared distance on raw f32 coords (bit-exact vs reference)
__device__ __forceinline__ float dist_v1(float px, float py, float pz,
                                         float cx, float cy, float cz) {
  const float dx = px - cx;
  const float dy = py - cy;
  const float dz = pz - cz;
  return __builtin_fmaf(dz, dz, __builtin_fmaf(dx, dx, dy * dy));
}

__global__ __launch_bounds__(THREADS_, 4) void fps_kernel(
    const float* __restrict__ x, float* __restrict__ out)
{
#pragma clang fp contract(off)
  const int b    = blockIdx.x;
  const int t    = threadIdx.x;
  const int lane = t & 63;
  const int wave = t >> 6;

  // parity-double-buffered per-wave argmax slots: one barrier per iteration
  __shared__ float s_v[2][NW_];
  __shared__ int   s_g[2][NW_];

  const float* xb  = x + (size_t)b * (N_ * 3);
  float* out_x     = out;                        // [B*K*3] f32 (bf16-grid values)
  float* out_batch = out + (size_t)B_ * K_ * 3;  // [B*K]   f32 cloud ids

  // batch output (buffer re-poisoned every call -> rewrite every call)
  {
    const float bb = (float)b;
    for (int i = t; i < K_; i += THREADS_) out_batch[b * K_ + i] = bb;
  }

  // Load this thread's 16 points, raw f32 (strided: g = s*1024 + t)
  float px[PTS_], py[PTS_], pz[PTS_], mind[PTS_];
#pragma unroll
  for (int s = 0; s < PTS_; ++s) {
    const int g = s * THREADS_ + t;
    px[s] = xb[3 * g + 0];
    py[s] = xb[3 * g + 1];
    pz[s] = xb[3 * g + 2];
  }

  // ---- iteration 0: seed = point 0 ----
  float cx = xb[0], cy = xb[1], cz = xb[2];
  if (t == 0) {
    const uint64_t o = ((uint64_t)b * K_) * 3;
    out_x[o + 0] = bfr(cx); out_x[o + 1] = bfr(cy); out_x[o + 2] = bfr(cz);
  }

  float bv = -1.0f; int bs = 0;
#pragma unroll
  for (int s = 0; s < PTS_; ++s) {
    const float d = dist_v1(px[s], py[s], pz[s], cx, cy, cz);
    mind[s] = d;
    if (d > bv) { bv = d; bs = s; }   // local-s tracking: cndmask w/ inline const
  }
  int bg = bs * THREADS_ + t;          // global index, ascending-s => first-index
  // wave-level (value, first-index) argmax reduction
#pragma unroll
  for (int m = 32; m >= 1; m >>= 1) {
    const float ov = __shfl_xor(bv, m, 64);
    const int   og = __shfl_xor(bg, m, 64);
    if (ov > bv || (ov == bv && og < bg)) { bv = ov; bg = og; }
  }
  if (lane == 0) { s_v[0][wave] = bv; s_g[0][wave] = bg; }
  __syncthreads();

  // ---- iterations 1..K-1 ----
  for (int j = 1; j < K_; ++j) {
    const int rp = (j - 1) & 1;
    const int wp = j & 1;

    // finalize block argmax of previous round (all threads redundantly;
    // uniform addresses -> LDS broadcast reads)
    float v = s_v[rp][0]; int g = s_g[rp][0];
#pragma unroll
    for (int w = 1; w < NW_; ++w) {
      const float ov = s_v[rp][w]; const int og = s_g[rp][w];
      if (ov > v || (ov == v && og < g)) { v = ov; g = og; }
    }

    // uniform (scalar) broadcast load of the chosen point's raw coords
    const int gu = __builtin_amdgcn_readfirstlane(g);
    cx = xb[3 * gu + 0];
    cy = xb[3 * gu + 1];
    cz = xb[3 * gu + 2];
    if (t == 0) {
      const uint64_t o = ((uint64_t)b * K_ + j) * 3;
      out_x[o + 0] = bfr(cx); out_x[o + 1] = bfr(cy); out_x[o + 2] = bfr(cz);
    }

    // update mind + fused local argmax scan for next round
    bv = -1.0f; bs = 0;
#pragma unroll
    for (int s = 0; s < PTS_; ++s) {
      const float d  = dist_v1(px[s], py[s], pz[s], cx, cy, cz);
      const float m2 = fminf(mind[s], d);
      mind[s] = m2;
      if (m2 > bv) { bv = m2; bs = s; }
    }
    bg = bs * THREADS_ + t;
#pragma unroll
    for (int m = 32; m >= 1; m >>= 1) {
      const float ov = __shfl_xor(bv, m, 64);
      const int   og = __shfl_xor(bg, m, 64);
      if (ov > bv || (ov == bv && og < bg)) { bv = ov; bg = og; }
    }
    if (lane == 0) { s_v[wp][wave] = bv; s_g[wp][wave] = bg; }
    __syncthreads();
  }
}

extern "C" void kernel_launch(void* const* d_in, const int* in_sizes, int n_in,
                              void* d_out, int out_size, void* d_ws, size_t ws_size,
                              hipStream_t stream) {
  const float* x = (const float*)d_in[0];  // f32, [B*N, 3]
  float* out     = (float*)d_out;          // f32: [B*K*3] coords + [B*K] batch
  (void)in_sizes; (void)n_in; (void)out_size; (void)d_ws; (void)ws_size;
  hipLaunchKernelGGL(fps_kernel, dim3(B_), dim3(THREADS_), 0, stream, x, out);
}

// Round 10
// 9204.640 us; speedup vs baseline: 1.2639x; 1.2639x over previous
//
#include <hip/hip_runtime.h>
#include <cstdint>

// Reference semantics (validated R8, absmax=0.0 — DO NOT change arithmetic):
//  - selection on RAW f32 coords, distance = fma(dz,dz, fma(dx,dx, dy*dy))
//    with dx/dy/dz plain f32 subs (XLA/LLVM FMA-contraction order);
//  - min/argmax exact, first-index tie-break;
//  - output coords bf16-RNE-rounded (ref Output-0 is bf16-grid), batch = float b.
#pragma clang fp contract(off)

#define B_ 16
#define N_ 16384
#define K_ 4096
#define THREADS_ 512
#define PTS_ (N_ / THREADS_)   // 32 points per thread
#define NW_ (THREADS_ / 64)    // 8 waves per block

// f32 -> bf16 RNE, returned as the bf16-representable f32 (finite inputs)
__device__ __forceinline__ float bfr(float f) {
  union { float f; uint32_t i; } c; c.f = f;
  c.i = (c.i + 0x7FFFu + ((c.i >> 16) & 1u)) & 0xFFFF0000u;
  return c.f;
}

// FMA-V1 squared distance on raw f32 coords (bit-exact vs reference)
__device__ __forceinline__ float dist_v1(float px, float py, float pz,
                                         float cx, float cy, float cz) {
  const float dx = px - cx;
  const float dy = py - cy;
  const float dz = pz - cz;
  return __builtin_fmaf(dz, dz, __builtin_fmaf(dx, dx, dy * dy));
}

// waves_per_eu(1,2): unified-register budget 512/min=512 regs/wave, so the
// 128-float point/mind arrays + temps (~180 regs) stay in ARCH VGPRs with no
// AGPR/scratch shuttling (R8/R9 regression: allocator split at 88/48 arch).
__global__ __attribute__((amdgpu_flat_work_group_size(THREADS_, THREADS_),
                          amdgpu_waves_per_eu(1, 2)))
void fps_kernel(const float* __restrict__ x, float* __restrict__ out)
{
#pragma clang fp contract(off)
  const int b    = blockIdx.x;
  const int t    = threadIdx.x;
  const int lane = t & 63;
  const int wave = t >> 6;

  // parity-double-buffered per-wave argmax slots: one barrier per iteration
  __shared__ float s_v[2][NW_];
  __shared__ int   s_g[2][NW_];

  const float* xb  = x + (size_t)b * (N_ * 3);
  float* out_x     = out;                        // [B*K*3] f32 (bf16-grid values)
  float* out_batch = out + (size_t)B_ * K_ * 3;  // [B*K]   f32 cloud ids

  // batch output (buffer re-poisoned every call -> rewrite every call)
  {
    const float bb = (float)b;
    for (int i = t; i < K_; i += THREADS_) out_batch[b * K_ + i] = bb;
  }

  // Load this thread's 32 points, raw f32 (strided: g = s*512 + t)
  float px[PTS_], py[PTS_], pz[PTS_], mind[PTS_];
#pragma unroll
  for (int s = 0; s < PTS_; ++s) {
    const int g = s * THREADS_ + t;
    px[s] = xb[3 * g + 0];
    py[s] = xb[3 * g + 1];
    pz[s] = xb[3 * g + 2];
  }

  // ---- iteration 0: seed = point 0 ----
  float cx = xb[0], cy = xb[1], cz = xb[2];
  if (t == 0) {
    const uint64_t o = ((uint64_t)b * K_) * 3;
    out_x[o + 0] = bfr(cx); out_x[o + 1] = bfr(cy); out_x[o + 2] = bfr(cz);
  }

  float bv = -1.0f; int bs = 0;
#pragma unroll
  for (int s = 0; s < PTS_; ++s) {
    const float d = dist_v1(px[s], py[s], pz[s], cx, cy, cz);
    mind[s] = d;
    if (d > bv) { bv = d; bs = s; }   // local-s tracking (inline-const cndmask)
  }
  int bg = bs * THREADS_ + t;          // ascending s => first-index within thread
  // wave-level (value, first-index) argmax reduction
#pragma unroll
  for (int m = 32; m >= 1; m >>= 1) {
    const float ov = __shfl_xor(bv, m, 64);
    const int   og = __shfl_xor(bg, m, 64);
    if (ov > bv || (ov == bv && og < bg)) { bv = ov; bg = og; }
  }
  if (lane == 0) { s_v[0][wave] = bv; s_g[0][wave] = bg; }
  __syncthreads();

  // ---- iterations 1..K-1 ----
  for (int j = 1; j < K_; ++j) {
    const int rp = (j - 1) & 1;
    const int wp = j & 1;

    // finalize block argmax of previous round (all threads redundantly;
    // uniform addresses -> LDS broadcast reads)
    float v = s_v[rp][0]; int g = s_g[rp][0];
#pragma unroll
    for (int w = 1; w < NW_; ++w) {
      const float ov = s_v[rp][w]; const int og = s_g[rp][w];
      if (ov > v || (ov == v && og < g)) { v = ov; g = og; }
    }

    // uniform (scalar) broadcast load of the chosen point's raw coords
    const int gu = __builtin_amdgcn_readfirstlane(g);
    cx = xb[3 * gu + 0];
    cy = xb[3 * gu + 1];
    cz = xb[3 * gu + 2];
    if (t == 0) {
      const uint64_t o = ((uint64_t)b * K_ + j) * 3;
      out_x[o + 0] = bfr(cx); out_x[o + 1] = bfr(cy); out_x[o + 2] = bfr(cz);
    }

    // update mind + fused local argmax scan for next round
    bv = -1.0f; bs = 0;
#pragma unroll
    for (int s = 0; s < PTS_; ++s) {
      const float d  = dist_v1(px[s], py[s], pz[s], cx, cy, cz);
      const float m2 = fminf(mind[s], d);
      mind[s] = m2;
      if (m2 > bv) { bv = m2; bs = s; }
    }
    bg = bs * THREADS_ + t;
#pragma unroll
    for (int m = 32; m >= 1; m >>= 1) {
      const float ov = __shfl_xor(bv, m, 64);
      const int   og = __shfl_xor(bg, m, 64);
      if (ov > bv || (ov == bv && og < bg)) { bv = ov; bg = og; }
    }
    if (lane == 0) { s_v[wp][wave] = bv; s_g[wp][wave] = bg; }
    __syncthreads();
  }
}

extern "C" void kernel_launch(void* const* d_in, const int* in_sizes, int n_in,
                              void* d_out, int out_size, void* d_ws, size_t ws_size,
                              hipStream_t stream) {
  const float* x = (const float*)d_in[0];  // f32, [B*N, 3]
  float* out     = (float*)d_out;          // f32: [B*K*3] coords + [B*K] batch
  (void)in_sizes; (void)n_in; (void)out_size; (void)d_ws; (void)ws_size;
  hipLaunchKernelGGL(fps_kernel, dim3(B_), dim3(THREADS_), 0, stream, x, out);
}

// Round 11
// 8009.456 us; speedup vs baseline: 1.4525x; 1.1492x over previous
//
#include <hip/hip_runtime.h>
#include <cstdint>

// Reference semantics (validated R8, absmax=0.0 — DO NOT change arithmetic):
//  - selection on RAW f32 coords, distance = fma(dz,dz, fma(dx,dx, dy*dy))
//    with dx/dy/dz plain f32 subs (XLA/LLVM FMA-contraction order);
//  - min/argmax exact, first-index tie-break;
//  - output coords bf16-RNE-rounded, batch = float b.
//
// R11 structural change: per-thread point/mind storage as NAMED SCALARS
// (X-macro), not arrays — forces SSA/register residency (R8-R10 showed the
// arrays never got promoted: VGPR_Count 88/48 with ~2x VALU + latency tail).
#pragma clang fp contract(off)

#define B_ 16
#define N_ 16384
#define K_ 4096
#define THREADS_ 512
#define PTS_ (N_ / THREADS_)   // 32 points per thread
#define NW_ (THREADS_ / 64)    // 8 waves per block

#define PTS_LIST(X) \
  X(0) X(1) X(2) X(3) X(4) X(5) X(6) X(7) \
  X(8) X(9) X(10) X(11) X(12) X(13) X(14) X(15) \
  X(16) X(17) X(18) X(19) X(20) X(21) X(22) X(23) \
  X(24) X(25) X(26) X(27) X(28) X(29) X(30) X(31)

// f32 -> bf16 RNE, returned as the bf16-representable f32 (finite inputs)
__device__ __forceinline__ float bfr(float f) {
  union { float f; uint32_t i; } c; c.f = f;
  c.i = (c.i + 0x7FFFu + ((c.i >> 16) & 1u)) & 0xFFFF0000u;
  return c.f;
}

__global__ __attribute__((amdgpu_flat_work_group_size(THREADS_, THREADS_),
                          amdgpu_waves_per_eu(1, 2)))
void fps_kernel(const float* __restrict__ x, float* __restrict__ out)
{
#pragma clang fp contract(off)
  const int b    = blockIdx.x;
  const int t    = threadIdx.x;
  const int lane = t & 63;
  const int wave = t >> 6;

  // parity-double-buffered per-wave argmax slots: one barrier per iteration
  __shared__ float s_v[2][NW_];
  __shared__ int   s_g[2][NW_];

  const float* xb  = x + (size_t)b * (N_ * 3);
  float* out_x     = out;                        // [B*K*3] f32 (bf16-grid values)
  float* out_batch = out + (size_t)B_ * K_ * 3;  // [B*K]   f32 cloud ids

  // batch output (buffer re-poisoned every call -> rewrite every call)
  {
    const float bb = (float)b;
    for (int i = t; i < K_; i += THREADS_) out_batch[b * K_ + i] = bb;
  }

  // Named per-point scalars (SSA -> guaranteed register residency)
#define DECLP(i) float px##i, py##i, pz##i, m##i;
  PTS_LIST(DECLP)
#undef DECLP

#define LOADP(i) { const float* p_ = xb + 3 * ((i) * THREADS_ + t); \
                   px##i = p_[0]; py##i = p_[1]; pz##i = p_[2];     \
                   m##i = __builtin_inff(); }
  PTS_LIST(LOADP)
#undef LOADP

  // Per-point update + fused local argmax (bit-exact FMA-V1 distance)
#define UPD(i) { const float dx_ = px##i - cx;                                  \
                 const float dy_ = py##i - cy;                                  \
                 const float dz_ = pz##i - cz;                                  \
                 const float d_  = __builtin_fmaf(dz_, dz_,                     \
                                   __builtin_fmaf(dx_, dx_, dy_ * dy_));        \
                 m##i = fminf(m##i, d_);                                        \
                 if (m##i > bv) { bv = m##i; bs = (i); } }

  // ---- iteration 0: seed = point 0 ----
  float cx = xb[0], cy = xb[1], cz = xb[2];
  if (t == 0) {
    const uint64_t o = ((uint64_t)b * K_) * 3;
    out_x[o + 0] = bfr(cx); out_x[o + 1] = bfr(cy); out_x[o + 2] = bfr(cz);
  }

  float bv = -1.0f; int bs = 0;
  PTS_LIST(UPD)                      // m = min(inf, d) = d; ascending i scan
  int bg = bs * THREADS_ + t;        // first-index within thread preserved
  // wave-level (value, first-index) argmax reduction
#pragma unroll
  for (int m = 32; m >= 1; m >>= 1) {
    const float ov = __shfl_xor(bv, m, 64);
    const int   og = __shfl_xor(bg, m, 64);
    if (ov > bv || (ov == bv && og < bg)) { bv = ov; bg = og; }
  }
  if (lane == 0) { s_v[0][wave] = bv; s_g[0][wave] = bg; }
  __syncthreads();

  // ---- iterations 1..K-1 ----
  for (int j = 1; j < K_; ++j) {
    const int rp = (j - 1) & 1;
    const int wp = j & 1;

    // finalize block argmax of previous round (uniform -> LDS broadcast reads)
    float v = s_v[rp][0]; int g = s_g[rp][0];
#pragma unroll
    for (int w = 1; w < NW_; ++w) {
      const float ov = s_v[rp][w]; const int og = s_g[rp][w];
      if (ov > v || (ov == v && og < g)) { v = ov; g = og; }
    }

    // uniform (scalar) broadcast load of the chosen point's raw coords
    const int gu = __builtin_amdgcn_readfirstlane(g);
    cx = xb[3 * gu + 0];
    cy = xb[3 * gu + 1];
    cz = xb[3 * gu + 2];
    if (t == 0) {
      const uint64_t o = ((uint64_t)b * K_ + j) * 3;
      out_x[o + 0] = bfr(cx); out_x[o + 1] = bfr(cy); out_x[o + 2] = bfr(cz);
    }

    // update mind + fused local argmax scan for next round
    bv = -1.0f; bs = 0;
    PTS_LIST(UPD)
    bg = bs * THREADS_ + t;
#pragma unroll
    for (int m = 32; m >= 1; m >>= 1) {
      const float ov = __shfl_xor(bv, m, 64);
      const int   og = __shfl_xor(bg, m, 64);
      if (ov > bv || (ov == bv && og < bg)) { bv = ov; bg = og; }
    }
    if (lane == 0) { s_v[wp][wave] = bv; s_g[wp][wave] = bg; }
    __syncthreads();
  }
#undef UPD
}

extern "C" void kernel_launch(void* const* d_in, const int* in_sizes, int n_in,
                              void* d_out, int out_size, void* d_ws, size_t ws_size,
                              hipStream_t stream) {
  const float* x = (const float*)d_in[0];  // f32, [B*N, 3]
  float* out     = (float*)d_out;          // f32: [B*K*3] coords + [B*K] batch
  (void)in_sizes; (void)n_in; (void)out_size; (void)d_ws; (void)ws_size;
  hipLaunchKernelGGL(fps_kernel, dim3(B_), dim3(THREADS_), 0, stream, x, out);
}